// Round 12
// baseline (110.383 us; speedup 1.0000x reference)
//
#include <hip/hip_runtime.h>
#include <hip/hip_bf16.h>
#include <type_traits>
#include <utility>

// Fused 2-layer Elman RNN + FC, round 12: R11 + read-once register-carried state.
// B=16384, T=28, IN=28, H1=128, H2=64, NC=10.
// 1024 blocks x 256 thr; block owns 16 batch rows; waves N-split-4;
// 2 barriers/step; prepass bf16 weights in d_ws; rcp-tanh; hoisted offsets.
// NEW vs R11:
//  - h1A[4]/h2A[2] A-frags carried in REGISTERS across phases: h1(t) read
//    ONCE (P2; feeds layer2 AND next P1 recurrence), h2(t) read ONCE (P3
//    after B2; feeds FC AND next P2 recurrence). 11 -> 6 b128 reads/step.
//    P1's MFMA chain starts on register operands (no ds_read at phase head).
//  - single-buffered h1s/h2s (register carry makes it race-free: every
//    buffer write/read pair is separated by B1/B2). LDS 15.4 -> 8.7 KB.
//  - t=0 peeled; steady loop t=1..27 branch-free.

#define NBLK 1024
#define NTHR 256

typedef float  f32x4 __attribute__((ext_vector_type(4)));
typedef short  s16x8 __attribute__((ext_vector_type(8)));
typedef __bf16 b16x8 __attribute__((ext_vector_type(8)));

template <typename V, typename = void> struct mfma_ok : std::false_type {};
template <typename V>
struct mfma_ok<V, std::void_t<decltype(__builtin_amdgcn_mfma_f32_16x16x32_bf16(
    std::declval<V>(), std::declval<V>(), std::declval<f32x4>(), 0, 0, 0))>>
    : std::true_type {};
using frag_t = std::conditional_t<mfma_ok<b16x8>::value, b16x8, s16x8>;

__device__ __forceinline__ f32x4 MFMA(frag_t a, frag_t b, f32x4 c) {
  return __builtin_amdgcn_mfma_f32_16x16x32_bf16(a, b, c, 0, 0, 0);
}

__device__ __forceinline__ unsigned short f2bf_n(float f) {  // native cvt (RNE)
  __bf16 h = (__bf16)f;
  return __builtin_bit_cast(unsigned short, h);
}
__device__ __forceinline__ frag_t packx(float4 a, float4 b) {
  s16x8 r;
  r[0]=(short)f2bf_n(a.x); r[1]=(short)f2bf_n(a.y); r[2]=(short)f2bf_n(a.z); r[3]=(short)f2bf_n(a.w);
  r[4]=(short)f2bf_n(b.x); r[5]=(short)f2bf_n(b.y); r[6]=(short)f2bf_n(b.z); r[7]=(short)f2bf_n(b.w);
  return __builtin_bit_cast(frag_t, r);
}
// tanh(v) = 1 - 2/(exp(2v)+1) with fast v_rcp_f32 (saturates correctly).
__device__ __forceinline__ float tanh_fast(float v) {
  float e = __expf(2.0f * v);
  return fmaf(-2.0f, __builtin_amdgcn_rcpf(e + 1.0f), 1.0f);
}

// ---- bf16 weight cache layout in d_ws (u16 elements) ----
#define OFF_WIH1 0        // [128][32]  (K padded 28->32 with zeros)
#define OFF_WHH1 4096     // [128][128]
#define OFF_WIH2 20480    // [64][128]
#define OFF_WHH2 28672    // [64][64]
#define OFF_WFC  32768    // [10][1792]
#define WS_U16   50688

__global__ void cvt_weights(const float* __restrict__ wih1, const float* __restrict__ whh1,
                            const float* __restrict__ wih2, const float* __restrict__ whh2,
                            const float* __restrict__ wfc,  unsigned short* __restrict__ ws)
{
  int i = blockIdx.x * 256 + threadIdx.x;
  if (i < 4096) {                       // W_ih1 padded
    int r = i >> 5, c = i & 31;
    ws[OFF_WIH1 + i] = (c < 28) ? f2bf_n(wih1[r * 28 + c]) : (unsigned short)0;
    return;
  }
  i -= 4096;
  if (i < 16384) { ws[OFF_WHH1 + i] = f2bf_n(whh1[i]); return; }
  i -= 16384;
  if (i < 8192)  { ws[OFF_WIH2 + i] = f2bf_n(wih2[i]); return; }
  i -= 8192;
  if (i < 4096)  { ws[OFF_WHH2 + i] = f2bf_n(whh2[i]); return; }
  i -= 4096;
  if (i < 17920) { ws[OFF_WFC + i] = f2bf_n(wfc[i]); return; }
}

__global__ __launch_bounds__(NTHR, 2)
void rnn_mfma12(const float* __restrict__ x,
                const unsigned short* __restrict__ ws,
                const float* __restrict__ b_ih1, const float* __restrict__ b_hh1,
                const float* __restrict__ b_ih2, const float* __restrict__ b_hh2,
                const float* __restrict__ b_fc,
                float* __restrict__ out)
{
  // LDS: 4352 + 2304 + 2048 = 8,704 B (single-buffered: register carry
  // makes it race-free, see header)
  __shared__ alignas(16) unsigned short h1s[16][136];
  __shared__ alignas(16) unsigned short h2s[16][72];
  __shared__ alignas(16) float red[2][16][16];

  const int tid  = threadIdx.x;
  const int wn   = tid >> 6;          // wave = N-split index 0..3
  const int lane = tid & 63;
  const int li   = lane & 15;         // A-row (batch) / D-col
  const int g    = lane >> 4;         // 0..3 k-group / D-row-group
  const int blk  = blockIdx.x;
  // XOR-16 column swizzle: (row,col) stored at col ^ (((row>>3)&1)<<4)
  const int swr  = ((li >> 3) & 1) << 4;          // reads:  row = li
  const int swv  = ((g  >> 1) & 1) << 4;          // writes: row = g*4+r

  // ---- weight B-frags ----
  const int n1 = wn * 32 + li;        // (+nt*16)
  const int n2 = wn * 16 + li;
  frag_t wB1[4][2], wBi1[2], wBi2[4], wB2[2];
  #pragma unroll
  for (int kt = 0; kt < 4; ++kt)
    #pragma unroll
    for (int nt = 0; nt < 2; ++nt)
      wB1[kt][nt] = *(const frag_t*)(ws + OFF_WHH1 + (n1 + nt * 16) * 128 + kt * 32 + g * 8);
  #pragma unroll
  for (int nt = 0; nt < 2; ++nt)
    wBi1[nt] = *(const frag_t*)(ws + OFF_WIH1 + (n1 + nt * 16) * 32 + g * 8);
  #pragma unroll
  for (int kt = 0; kt < 4; ++kt)
    wBi2[kt] = *(const frag_t*)(ws + OFF_WIH2 + n2 * 128 + kt * 32 + g * 8);
  #pragma unroll
  for (int kt = 0; kt < 2; ++kt)
    wB2[kt] = *(const frag_t*)(ws + OFF_WHH2 + n2 * 64 + kt * 32 + g * 8);

  float b1v[2];
  b1v[0] = b_ih1[n1] + b_hh1[n1];
  b1v[1] = b_ih1[n1 + 16] + b_hh1[n1 + 16];
  const float b2v = b_ih2[n2] + b_hh2[n2];

  const float* xrow = x + (size_t)(blk * 16 + li) * 784 + g * 8;
  const int    cls  = (li < 10) ? li : 0;
  const unsigned short* wfp = ws + OFF_WFC + cls * 1792 + (wn & 1) * 32 + g * 8;

  // loop-invariant LDS offsets
  const int rk[4] = { (g * 8) ^ swr, (32 + g * 8) ^ swr,
                      (64 + g * 8) ^ swr, (96 + g * 8) ^ swr };
  const int wcA0 = ((wn * 32) ^ swv) + li;        // L1 store cols
  const int wcA1 = ((wn * 32 + 16) ^ swv) + li;
  const int wcB  = ((wn * 16) ^ swv) + li;        // L2 store col

  f32x4 fca = {0.f, 0.f, 0.f, 0.f};
  frag_t h1A[4], h2A[2];              // register-carried A-frags of h1(t)/h2(t)

  // ================= t = 0 (peeled: no recurrences) =================
  {
    float4 xa = *(const float4*)(xrow);
    float4 xb = float4{0.f, 0.f, 0.f, 0.f};
    if (g < 3) xb = *(const float4*)(xrow + 4);
    frag_t xA = packx(xa, xb);
    f32x4 acc1[2];
    acc1[0] = f32x4{b1v[0], b1v[0], b1v[0], b1v[0]};
    acc1[1] = f32x4{b1v[1], b1v[1], b1v[1], b1v[1]};
    acc1[0] = MFMA(xA, wBi1[0], acc1[0]);
    acc1[1] = MFMA(xA, wBi1[1], acc1[1]);
    #pragma unroll
    for (int r = 0; r < 4; ++r) h1s[g * 4 + r][wcA0] = f2bf_n(tanh_fast(acc1[0][r]));
    #pragma unroll
    for (int r = 0; r < 4; ++r) h1s[g * 4 + r][wcA1] = f2bf_n(tanh_fast(acc1[1][r]));
    __syncthreads();   // B1(0)

    #pragma unroll
    for (int kt = 0; kt < 4; ++kt) h1A[kt] = *(const frag_t*)&h1s[li][rk[kt]];
    f32x4 acc2 = f32x4{b2v, b2v, b2v, b2v};
    #pragma unroll
    for (int kt = 0; kt < 4; ++kt) acc2 = MFMA(h1A[kt], wBi2[kt], acc2);
    #pragma unroll
    for (int r = 0; r < 4; ++r) h2s[g * 4 + r][wcB] = f2bf_n(tanh_fast(acc2[r]));
    __syncthreads();   // B2(0)

    h2A[0] = *(const frag_t*)&h2s[li][rk[0]];
    h2A[1] = *(const frag_t*)&h2s[li][rk[1]];
    if (wn < 2) {
      frag_t bfc = *(const frag_t*)(wfp);
      fca = MFMA(h2A[wn], bfc, fca);
    }
  }

  // ================= t = 1 .. 27 (branch-free) =================
  #pragma unroll 1
  for (int t = 1; t < 28; ++t) {
    // ---- P1: layer 1 entirely from registers (h1A = h1(t-1)) ----
    float4 xa = *(const float4*)(xrow + t * 28);
    float4 xb = float4{0.f, 0.f, 0.f, 0.f};
    if (g < 3) xb = *(const float4*)(xrow + t * 28 + 4);

    f32x4 acc1[2];
    acc1[0] = f32x4{b1v[0], b1v[0], b1v[0], b1v[0]};
    acc1[1] = f32x4{b1v[1], b1v[1], b1v[1], b1v[1]};
    #pragma unroll
    for (int kt = 0; kt < 4; ++kt) {
      acc1[0] = MFMA(h1A[kt], wB1[kt][0], acc1[0]);
      acc1[1] = MFMA(h1A[kt], wB1[kt][1], acc1[1]);
    }
    {
      frag_t xA = packx(xa, xb);
      acc1[0] = MFMA(xA, wBi1[0], acc1[0]);
      acc1[1] = MFMA(xA, wBi1[1], acc1[1]);
    }
    #pragma unroll
    for (int r = 0; r < 4; ++r) h1s[g * 4 + r][wcA0] = f2bf_n(tanh_fast(acc1[0][r]));
    #pragma unroll
    for (int r = 0; r < 4; ++r) h1s[g * 4 + r][wcA1] = f2bf_n(tanh_fast(acc1[1][r]));

    __syncthreads();   // B1(t): h1(t) visible

    // ---- P2: single read of h1(t); layer 2 (h2A = h2(t-1)) ----
    #pragma unroll
    for (int kt = 0; kt < 4; ++kt) h1A[kt] = *(const frag_t*)&h1s[li][rk[kt]];

    f32x4 acc2 = f32x4{b2v, b2v, b2v, b2v};
    #pragma unroll
    for (int kt = 0; kt < 4; ++kt) acc2 = MFMA(h1A[kt], wBi2[kt], acc2);
    #pragma unroll
    for (int kt = 0; kt < 2; ++kt) acc2 = MFMA(h2A[kt], wB2[kt], acc2);
    #pragma unroll
    for (int r = 0; r < 4; ++r) h2s[g * 4 + r][wcB] = f2bf_n(tanh_fast(acc2[r]));

    __syncthreads();   // B2(t): h2(t) visible

    // ---- P3: single read of h2(t); FC(t) ----
    h2A[0] = *(const frag_t*)&h2s[li][rk[0]];
    h2A[1] = *(const frag_t*)&h2s[li][rk[1]];
    if (wn < 2) {
      frag_t bfc = *(const frag_t*)(wfp + t * 64);
      fca = MFMA(h2A[wn], bfc, fca);
    }
  }

  // ---- epilogue: 2-way K-reduce + bias + store ----
  if (wn < 2) {
    #pragma unroll
    for (int r = 0; r < 4; ++r)
      red[wn][g * 4 + r][li] = fca[r];
  }
  __syncthreads();
  if (tid < 160) {
    const int b = tid / 10, c = tid - b * 10;
    out[(size_t)(blk * 16 + b) * 10 + c] = red[0][b][c] + red[1][b][c] + b_fc[c];
  }
}

extern "C" void kernel_launch(void* const* d_in, const int* in_sizes, int n_in,
                              void* d_out, int out_size, void* d_ws, size_t ws_size,
                              hipStream_t stream) {
  const float* x     = (const float*)d_in[0];
  const float* W_ih1 = (const float*)d_in[1];
  const float* W_hh1 = (const float*)d_in[2];
  const float* b_ih1 = (const float*)d_in[3];
  const float* b_hh1 = (const float*)d_in[4];
  const float* W_ih2 = (const float*)d_in[5];
  const float* W_hh2 = (const float*)d_in[6];
  const float* b_ih2 = (const float*)d_in[7];
  const float* b_hh2 = (const float*)d_in[8];
  const float* W_fc  = (const float*)d_in[9];
  const float* b_fc  = (const float*)d_in[10];
  unsigned short* ws = (unsigned short*)d_ws;

  cvt_weights<<<(WS_U16 + 255) / 256, 256, 0, stream>>>(W_ih1, W_hh1, W_ih2, W_hh2, W_fc, ws);
  rnn_mfma12<<<NBLK, NTHR, 0, stream>>>(x, ws, b_ih1, b_hh1, b_ih2, b_hh2, b_fc,
                                        (float*)d_out);
}

// Round 15
// 75.176 us; speedup vs baseline: 1.4683x; 1.4683x over previous
//
#include <hip/hip_runtime.h>
#include <hip/hip_bf16.h>
#include <type_traits>
#include <utility>

// Fused 2-layer Elman RNN + FC, round 15 (= round 13 kernel, resubmitted
// twice; R13/R14 benches died with container-infra errors before running).
// R11 chassis + 1-step register prefetch of x(t+1) and W_fc(t+1).
// B=16384, T=28, IN=28, H1=128, H2=64, NC=10.
// 1024 blocks x 256 thr; block owns 16 batch rows; waves N-split-4;
// 2 barriers/step; prepass bf16 weights in d_ws; rcp-tanh; unroll-2 with
// hoisted LDS offsets (all R11, measured 62.5us).
// NEW vs R11: x(t) was loaded at P1 head and consumed ~10 insts later ->
// ~900cy HBM latency exposed once per step (~10us total). Now x(t+1) is
// issued right after x(t) is packed (consumed a full step later); same for
// the FC weight frag (L2, ~200cy). Register cost ~+12 VGPR.

#define NBLK 1024
#define NTHR 256

typedef float  f32x4 __attribute__((ext_vector_type(4)));
typedef short  s16x8 __attribute__((ext_vector_type(8)));
typedef __bf16 b16x8 __attribute__((ext_vector_type(8)));

template <typename V, typename = void> struct mfma_ok : std::false_type {};
template <typename V>
struct mfma_ok<V, std::void_t<decltype(__builtin_amdgcn_mfma_f32_16x16x32_bf16(
    std::declval<V>(), std::declval<V>(), std::declval<f32x4>(), 0, 0, 0))>>
    : std::true_type {};
using frag_t = std::conditional_t<mfma_ok<b16x8>::value, b16x8, s16x8>;

__device__ __forceinline__ f32x4 MFMA(frag_t a, frag_t b, f32x4 c) {
  return __builtin_amdgcn_mfma_f32_16x16x32_bf16(a, b, c, 0, 0, 0);
}

__device__ __forceinline__ unsigned short f2bf_n(float f) {  // native cvt (RNE)
  __bf16 h = (__bf16)f;
  return __builtin_bit_cast(unsigned short, h);
}
__device__ __forceinline__ frag_t packx(float4 a, float4 b) {
  s16x8 r;
  r[0]=(short)f2bf_n(a.x); r[1]=(short)f2bf_n(a.y); r[2]=(short)f2bf_n(a.z); r[3]=(short)f2bf_n(a.w);
  r[4]=(short)f2bf_n(b.x); r[5]=(short)f2bf_n(b.y); r[6]=(short)f2bf_n(b.z); r[7]=(short)f2bf_n(b.w);
  return __builtin_bit_cast(frag_t, r);
}
// tanh(v) = 1 - 2/(exp(2v)+1) with fast v_rcp_f32 (saturates correctly).
__device__ __forceinline__ float tanh_fast(float v) {
  float e = __expf(2.0f * v);
  return fmaf(-2.0f, __builtin_amdgcn_rcpf(e + 1.0f), 1.0f);
}

// ---- bf16 weight cache layout in d_ws (u16 elements) ----
#define OFF_WIH1 0        // [128][32]  (K padded 28->32 with zeros)
#define OFF_WHH1 4096     // [128][128]
#define OFF_WIH2 20480    // [64][128]
#define OFF_WHH2 28672    // [64][64]
#define OFF_WFC  32768    // [10][1792]
#define WS_U16   50688

__global__ void cvt_weights(const float* __restrict__ wih1, const float* __restrict__ whh1,
                            const float* __restrict__ wih2, const float* __restrict__ whh2,
                            const float* __restrict__ wfc,  unsigned short* __restrict__ ws)
{
  int i = blockIdx.x * 256 + threadIdx.x;
  if (i < 4096) {                       // W_ih1 padded
    int r = i >> 5, c = i & 31;
    ws[OFF_WIH1 + i] = (c < 28) ? f2bf_n(wih1[r * 28 + c]) : (unsigned short)0;
    return;
  }
  i -= 4096;
  if (i < 16384) { ws[OFF_WHH1 + i] = f2bf_n(whh1[i]); return; }
  i -= 16384;
  if (i < 8192)  { ws[OFF_WIH2 + i] = f2bf_n(wih2[i]); return; }
  i -= 8192;
  if (i < 4096)  { ws[OFF_WHH2 + i] = f2bf_n(whh2[i]); return; }
  i -= 4096;
  if (i < 17920) { ws[OFF_WFC + i] = f2bf_n(wfc[i]); return; }
}

__global__ __launch_bounds__(NTHR, 2)
void rnn_mfma15(const float* __restrict__ x,
                const unsigned short* __restrict__ ws,
                const float* __restrict__ b_ih1, const float* __restrict__ b_hh1,
                const float* __restrict__ b_ih2, const float* __restrict__ b_hh2,
                const float* __restrict__ b_fc,
                float* __restrict__ out)
{
  // LDS: 8704 + 4608 + 2048 = 15,360 B
  __shared__ alignas(16) unsigned short h1s[2][16][136];
  __shared__ alignas(16) unsigned short h2s[2][16][72];
  __shared__ alignas(16) float red[2][16][16];

  const int tid  = threadIdx.x;
  const int wn   = tid >> 6;          // wave = N-split index 0..3
  const int lane = tid & 63;
  const int li   = lane & 15;         // A-row (batch) / D-col
  const int g    = lane >> 4;         // 0..3 k-group / D-row-group
  const int blk  = blockIdx.x;
  // XOR-16 column swizzle: (row,col) stored at col ^ (((row>>3)&1)<<4)
  const int swr  = ((li >> 3) & 1) << 4;          // reads:  row = li
  const int swv  = ((g  >> 1) & 1) << 4;          // writes: row = g*4+r

  // ---- weight B-frags ----
  const int n1 = wn * 32 + li;        // (+nt*16)
  const int n2 = wn * 16 + li;
  frag_t wB1[4][2], wBi1[2], wBi2[4], wB2[2];
  #pragma unroll
  for (int kt = 0; kt < 4; ++kt)
    #pragma unroll
    for (int nt = 0; nt < 2; ++nt)
      wB1[kt][nt] = *(const frag_t*)(ws + OFF_WHH1 + (n1 + nt * 16) * 128 + kt * 32 + g * 8);
  #pragma unroll
  for (int nt = 0; nt < 2; ++nt)
    wBi1[nt] = *(const frag_t*)(ws + OFF_WIH1 + (n1 + nt * 16) * 32 + g * 8);
  #pragma unroll
  for (int kt = 0; kt < 4; ++kt)
    wBi2[kt] = *(const frag_t*)(ws + OFF_WIH2 + n2 * 128 + kt * 32 + g * 8);
  #pragma unroll
  for (int kt = 0; kt < 2; ++kt)
    wB2[kt] = *(const frag_t*)(ws + OFF_WHH2 + n2 * 64 + kt * 32 + g * 8);

  float b1v[2];
  b1v[0] = b_ih1[n1] + b_hh1[n1];
  b1v[1] = b_ih1[n1 + 16] + b_hh1[n1 + 16];
  const float b2v = b_ih2[n2] + b_hh2[n2];

  const float* xrow = x + (size_t)(blk * 16 + li) * 784 + g * 8;
  const int    cls  = (li < 10) ? li : 0;
  const unsigned short* wfp = ws + OFF_WFC + cls * 1792 + (wn & 1) * 32 + g * 8;

  // loop-invariant LDS offsets (compile-time cb via unroll-2 below)
  const int rk[4] = { (g * 8) ^ swr, (32 + g * 8) ^ swr,
                      (64 + g * 8) ^ swr, (96 + g * 8) ^ swr };
  const int rfc  = (wn * 32 + g * 8) ^ swr;       // FC read (waves 0,1)
  const int wcA0 = ((wn * 32) ^ swv) + li;        // L1 store cols
  const int wcA1 = ((wn * 32 + 16) ^ swv) + li;
  const int wcB  = ((wn * 16) ^ swv) + li;        // L2 store col

  f32x4 fca = {0.f, 0.f, 0.f, 0.f};

  // ---- prefetch registers: x(0) and FC weight frag(0) ----
  float4 xa_c = *(const float4*)(xrow);
  float4 xb_c = float4{0.f, 0.f, 0.f, 0.f};
  if (g < 3) xb_c = *(const float4*)(xrow + 4);
  frag_t bfc_c;
  if (wn < 2) bfc_c = *(const frag_t*)(wfp);

#define RNN_STEP(CB, PB, T)                                                   \
  {                                                                           \
    const int t_ = (T);                                                       \
    /* ---- layer 1: pack prefetched x(t), then issue x(t+1) loads ---- */    \
    frag_t xA = packx(xa_c, xb_c);                                            \
    if (t_ < 27) {                                                            \
      xa_c = *(const float4*)(xrow + (t_ + 1) * 28);                          \
      if (g < 3) xb_c = *(const float4*)(xrow + (t_ + 1) * 28 + 4);           \
    }                                                                         \
    f32x4 acc1[2];                                                            \
    acc1[0] = f32x4{b1v[0], b1v[0], b1v[0], b1v[0]};                          \
    acc1[1] = f32x4{b1v[1], b1v[1], b1v[1], b1v[1]};                          \
    if (t_ > 0) {                                                             \
      _Pragma("unroll")                                                       \
      for (int kt = 0; kt < 4; ++kt) {                                        \
        frag_t a = *(const frag_t*)&h1s[PB][li][rk[kt]];                      \
        acc1[0] = MFMA(a, wB1[kt][0], acc1[0]);                               \
        acc1[1] = MFMA(a, wB1[kt][1], acc1[1]);                               \
      }                                                                       \
    }                                                                         \
    acc1[0] = MFMA(xA, wBi1[0], acc1[0]);                                     \
    acc1[1] = MFMA(xA, wBi1[1], acc1[1]);                                     \
    _Pragma("unroll")                                                         \
    for (int r = 0; r < 4; ++r)                                               \
      h1s[CB][g * 4 + r][wcA0] = f2bf_n(tanh_fast(acc1[0][r]));               \
    _Pragma("unroll")                                                         \
    for (int r = 0; r < 4; ++r)                                               \
      h1s[CB][g * 4 + r][wcA1] = f2bf_n(tanh_fast(acc1[1][r]));               \
    __syncthreads();   /* B1: h1(t) visible */                                \
    /* ---- layer 2 ---- */                                                   \
    f32x4 acc2 = f32x4{b2v, b2v, b2v, b2v};                                   \
    _Pragma("unroll")                                                         \
    for (int kt = 0; kt < 4; ++kt) {                                          \
      frag_t a = *(const frag_t*)&h1s[CB][li][rk[kt]];                        \
      acc2 = MFMA(a, wBi2[kt], acc2);                                         \
    }                                                                         \
    if (t_ > 0) {                                                             \
      _Pragma("unroll")                                                       \
      for (int kt = 0; kt < 2; ++kt) {                                        \
        frag_t a = *(const frag_t*)&h2s[PB][li][rk[kt]];                      \
        acc2 = MFMA(a, wB2[kt], acc2);                                        \
      }                                                                       \
    }                                                                         \
    _Pragma("unroll")                                                         \
    for (int r = 0; r < 4; ++r)                                               \
      h2s[CB][g * 4 + r][wcB] = f2bf_n(tanh_fast(acc2[r]));                   \
    __syncthreads();   /* B2: h2(t) visible */                                \
    /* ---- FC (waves 0,1): use prefetched frag, then fetch next ---- */      \
    if (wn < 2) {                                                             \
      frag_t a = *(const frag_t*)&h2s[CB][li][rfc];                           \
      fca = MFMA(a, bfc_c, fca);                                              \
      if (t_ < 27) bfc_c = *(const frag_t*)(wfp + (t_ + 1) * 64);             \
    }                                                                         \
  }

  #pragma unroll 1
  for (int t2 = 0; t2 < 28; t2 += 2) {
    RNN_STEP(0, 1, t2)
    RNN_STEP(1, 0, t2 + 1)
  }
#undef RNN_STEP

  // ---- epilogue: 2-way K-reduce + bias + store ----
  if (wn < 2) {
    #pragma unroll
    for (int r = 0; r < 4; ++r)
      red[wn][g * 4 + r][li] = fca[r];
  }
  __syncthreads();
  if (tid < 160) {
    const int b = tid / 10, c = tid - b * 10;
    out[(size_t)(blk * 16 + b) * 10 + c] = red[0][b][c] + red[1][b][c] + b_fc[c];
  }
}

extern "C" void kernel_launch(void* const* d_in, const int* in_sizes, int n_in,
                              void* d_out, int out_size, void* d_ws, size_t ws_size,
                              hipStream_t stream) {
  const float* x     = (const float*)d_in[0];
  const float* W_ih1 = (const float*)d_in[1];
  const float* W_hh1 = (const float*)d_in[2];
  const float* b_ih1 = (const float*)d_in[3];
  const float* b_hh1 = (const float*)d_in[4];
  const float* W_ih2 = (const float*)d_in[5];
  const float* W_hh2 = (const float*)d_in[6];
  const float* b_ih2 = (const float*)d_in[7];
  const float* b_hh2 = (const float*)d_in[8];
  const float* W_fc  = (const float*)d_in[9];
  const float* b_fc  = (const float*)d_in[10];
  unsigned short* ws = (unsigned short*)d_ws;

  cvt_weights<<<(WS_U16 + 255) / 256, 256, 0, stream>>>(W_ih1, W_hh1, W_ih2, W_hh2, W_fc, ws);
  rnn_mfma15<<<NBLK, NTHR, 0, stream>>>(x, ws, b_ih1, b_hh1, b_ih2, b_hh2, b_fc,
                                        (float*)d_out);
}

// Round 17
// 72.340 us; speedup vs baseline: 1.5259x; 1.0392x over previous
//
#include <hip/hip_runtime.h>
#include <hip/hip_bf16.h>
#include <type_traits>
#include <utility>

// Fused 2-layer Elman RNN + FC, round 17 (= round 16 with the pk2bf compile
// fix: __hip_bfloat162 isn't trivially copyable -> build the packed u32 from
// two native u16 casts instead of bit_cast).
// R11 chassis + phase-local VALU cuts.
// B=16384, T=28, IN=28, H1=128, H2=64, NC=10.
// 1024 blocks x 256 thr; block owns 16 batch rows; waves N-split-4;
// 2 barriers/step; prepass bf16 weights in d_ws; rcp-tanh; unroll-2 with
// hoisted LDS offsets (R11, measured 62.5us best).
// NEW vs R11 (both phase-local; R12/R15 taught: no cross-barrier registers):
//  1. tanh via exp2f(v*2log2e): 1 mul + v_exp (was 2 muls + v_exp).
//  2. L1 N-interleave: lane li owns units {wn*32+2li, 2li+1} (weight/bias
//     load indices permuted; storage stays natural) -> the 2 tanh outputs
//     are address-adjacent -> packed u32 LDS write: 8 b16-writes become
//     4 b32-writes, write banks exactly 2-way (free).

#define NBLK 1024
#define NTHR 256

typedef float  f32x4 __attribute__((ext_vector_type(4)));
typedef short  s16x8 __attribute__((ext_vector_type(8)));
typedef __bf16 b16x8 __attribute__((ext_vector_type(8)));

template <typename V, typename = void> struct mfma_ok : std::false_type {};
template <typename V>
struct mfma_ok<V, std::void_t<decltype(__builtin_amdgcn_mfma_f32_16x16x32_bf16(
    std::declval<V>(), std::declval<V>(), std::declval<f32x4>(), 0, 0, 0))>>
    : std::true_type {};
using frag_t = std::conditional_t<mfma_ok<b16x8>::value, b16x8, s16x8>;

__device__ __forceinline__ f32x4 MFMA(frag_t a, frag_t b, f32x4 c) {
  return __builtin_amdgcn_mfma_f32_16x16x32_bf16(a, b, c, 0, 0, 0);
}

__device__ __forceinline__ unsigned short f2bf_n(float f) {  // native cvt (RNE)
  __bf16 h = (__bf16)f;
  return __builtin_bit_cast(unsigned short, h);
}
__device__ __forceinline__ unsigned int pk2bf(float lo, float hi) {
  return (unsigned int)f2bf_n(lo) | ((unsigned int)f2bf_n(hi) << 16);
}
__device__ __forceinline__ frag_t packx(float4 a, float4 b) {
  s16x8 r;
  r[0]=(short)f2bf_n(a.x); r[1]=(short)f2bf_n(a.y); r[2]=(short)f2bf_n(a.z); r[3]=(short)f2bf_n(a.w);
  r[4]=(short)f2bf_n(b.x); r[5]=(short)f2bf_n(b.y); r[6]=(short)f2bf_n(b.z); r[7]=(short)f2bf_n(b.w);
  return __builtin_bit_cast(frag_t, r);
}
// tanh(v) = 1 - 2/(exp2(v*2log2e)+1); v_exp_f32 IS exp2 -> one mul saved.
__device__ __forceinline__ float tanh_fast(float v) {
  float e = exp2f(v * 2.885390081777927f);   // 2*log2(e)
  return fmaf(-2.0f, __builtin_amdgcn_rcpf(e + 1.0f), 1.0f);
}

// ---- bf16 weight cache layout in d_ws (u16 elements) ----
#define OFF_WIH1 0        // [128][32]  (K padded 28->32 with zeros)
#define OFF_WHH1 4096     // [128][128]
#define OFF_WIH2 20480    // [64][128]
#define OFF_WHH2 28672    // [64][64]
#define OFF_WFC  32768    // [10][1792]
#define WS_U16   50688

__global__ void cvt_weights(const float* __restrict__ wih1, const float* __restrict__ whh1,
                            const float* __restrict__ wih2, const float* __restrict__ whh2,
                            const float* __restrict__ wfc,  unsigned short* __restrict__ ws)
{
  int i = blockIdx.x * 256 + threadIdx.x;
  if (i < 4096) {                       // W_ih1 padded
    int r = i >> 5, c = i & 31;
    ws[OFF_WIH1 + i] = (c < 28) ? f2bf_n(wih1[r * 28 + c]) : (unsigned short)0;
    return;
  }
  i -= 4096;
  if (i < 16384) { ws[OFF_WHH1 + i] = f2bf_n(whh1[i]); return; }
  i -= 16384;
  if (i < 8192)  { ws[OFF_WIH2 + i] = f2bf_n(wih2[i]); return; }
  i -= 8192;
  if (i < 4096)  { ws[OFF_WHH2 + i] = f2bf_n(whh2[i]); return; }
  i -= 4096;
  if (i < 17920) { ws[OFF_WFC + i] = f2bf_n(wfc[i]); return; }
}

__global__ __launch_bounds__(NTHR, 2)
void rnn_mfma17(const float* __restrict__ x,
                const unsigned short* __restrict__ ws,
                const float* __restrict__ b_ih1, const float* __restrict__ b_hh1,
                const float* __restrict__ b_ih2, const float* __restrict__ b_hh2,
                const float* __restrict__ b_fc,
                float* __restrict__ out)
{
  // LDS: 8704 + 4608 + 2048 = 15,360 B
  __shared__ alignas(16) unsigned int   h1s32[2][16][68];   // = u16 [16][136]
  __shared__ alignas(16) unsigned short h2s[2][16][72];
  __shared__ alignas(16) float red[2][16][16];

  const int tid  = threadIdx.x;
  const int wn   = tid >> 6;          // wave = N-split index 0..3
  const int lane = tid & 63;
  const int li   = lane & 15;         // A-row (batch) / D-col
  const int g    = lane >> 4;         // 0..3 k-group / D-row-group
  const int blk  = blockIdx.x;
  // swizzle: stored u16 col = unit ^ (16 * f(row)), f(row) = (row>>3)&1.
  const int swr  = ((li >> 3) & 1) << 4;          // reads:  row = li
  const int swv  = ((g  >> 1) & 1);               // writes: row = g*4+r (bit3 = g>>1)

  // ---- weight B-frags (L1 N-interleaved: lane li holds units 2li, 2li+1) ----
  const int u1 = wn * 32 + 2 * li;    // L1 unit pair base (+nt)
  const int n2 = wn * 16 + li;        // L2 col (unchanged)
  frag_t wB1[4][2], wBi1[2], wBi2[4], wB2[2];
  #pragma unroll
  for (int kt = 0; kt < 4; ++kt)
    #pragma unroll
    for (int nt = 0; nt < 2; ++nt)
      wB1[kt][nt] = *(const frag_t*)(ws + OFF_WHH1 + (u1 + nt) * 128 + kt * 32 + g * 8);
  #pragma unroll
  for (int nt = 0; nt < 2; ++nt)
    wBi1[nt] = *(const frag_t*)(ws + OFF_WIH1 + (u1 + nt) * 32 + g * 8);
  #pragma unroll
  for (int kt = 0; kt < 4; ++kt)
    wBi2[kt] = *(const frag_t*)(ws + OFF_WIH2 + n2 * 128 + kt * 32 + g * 8);
  #pragma unroll
  for (int kt = 0; kt < 2; ++kt)
    wB2[kt] = *(const frag_t*)(ws + OFF_WHH2 + n2 * 64 + kt * 32 + g * 8);

  float b1v[2];
  b1v[0] = b_ih1[u1] + b_hh1[u1];
  b1v[1] = b_ih1[u1 + 1] + b_hh1[u1 + 1];
  const float b2v = b_ih2[n2] + b_hh2[n2];

  const float* xrow = x + (size_t)(blk * 16 + li) * 784 + g * 8;
  const int    cls  = (li < 10) ? li : 0;
  const unsigned short* wfp = ws + OFF_WFC + cls * 1792 + (wn & 1) * 32 + g * 8;

  // loop-invariant LDS offsets
  const int rk[4] = { (g * 8) ^ swr, (32 + g * 8) ^ swr,
                      (64 + g * 8) ^ swr, (96 + g * 8) ^ swr };
  const int rfc  = (wn * 32 + g * 8) ^ swr;          // FC read (waves 0,1)
  const int wc32 = (wn * 16 + li) ^ (swv << 3);      // L1 b32 write index
  const int wcB  = ((wn * 16) ^ (swv << 4)) + li;    // L2 store col (u16)

  f32x4 fca = {0.f, 0.f, 0.f, 0.f};

#define RNN_STEP(CB, PB, T)                                                   \
  {                                                                           \
    const int t_ = (T);                                                       \
    /* ---- layer 1 ---- */                                                   \
    float4 xa = *(const float4*)(xrow + t_ * 28);                             \
    float4 xb = float4{0.f, 0.f, 0.f, 0.f};                                   \
    if (g < 3) xb = *(const float4*)(xrow + t_ * 28 + 4);                     \
    f32x4 acc1[2];                                                            \
    acc1[0] = f32x4{b1v[0], b1v[0], b1v[0], b1v[0]};                          \
    acc1[1] = f32x4{b1v[1], b1v[1], b1v[1], b1v[1]};                          \
    if (t_ > 0) {                                                             \
      _Pragma("unroll")                                                       \
      for (int kt = 0; kt < 4; ++kt) {                                        \
        frag_t a = *(const frag_t*)((const unsigned short*)&h1s32[PB][li][0]  \
                                    + rk[kt]);                                \
        acc1[0] = MFMA(a, wB1[kt][0], acc1[0]);                               \
        acc1[1] = MFMA(a, wB1[kt][1], acc1[1]);                               \
      }                                                                       \
    }                                                                         \
    {                                                                         \
      frag_t xA = packx(xa, xb);                                              \
      acc1[0] = MFMA(xA, wBi1[0], acc1[0]);                                   \
      acc1[1] = MFMA(xA, wBi1[1], acc1[1]);                                   \
    }                                                                         \
    _Pragma("unroll")                                                         \
    for (int r = 0; r < 4; ++r)                                               \
      h1s32[CB][g * 4 + r][wc32] =                                            \
          pk2bf(tanh_fast(acc1[0][r]), tanh_fast(acc1[1][r]));                \
    __syncthreads();   /* B1: h1(t) visible */                                \
    /* ---- layer 2 ---- */                                                   \
    f32x4 acc2 = f32x4{b2v, b2v, b2v, b2v};                                   \
    _Pragma("unroll")                                                         \
    for (int kt = 0; kt < 4; ++kt) {                                          \
      frag_t a = *(const frag_t*)((const unsigned short*)&h1s32[CB][li][0]    \
                                  + rk[kt]);                                  \
      acc2 = MFMA(a, wBi2[kt], acc2);                                         \
    }                                                                         \
    if (t_ > 0) {                                                             \
      _Pragma("unroll")                                                       \
      for (int kt = 0; kt < 2; ++kt) {                                        \
        frag_t a = *(const frag_t*)&h2s[PB][li][rk[kt]];                      \
        acc2 = MFMA(a, wB2[kt], acc2);                                        \
      }                                                                       \
    }                                                                         \
    _Pragma("unroll")                                                         \
    for (int r = 0; r < 4; ++r)                                               \
      h2s[CB][g * 4 + r][wcB] = f2bf_n(tanh_fast(acc2[r]));                   \
    __syncthreads();   /* B2: h2(t) visible */                                \
    /* ---- FC accumulation (waves 0,1 split K=64) ---- */                    \
    if (wn < 2) {                                                             \
      frag_t a   = *(const frag_t*)&h2s[CB][li][rfc];                         \
      frag_t bfc = *(const frag_t*)(wfp + t_ * 64);                           \
      fca = MFMA(a, bfc, fca);                                                \
    }                                                                         \
  }

  #pragma unroll 1
  for (int t2 = 0; t2 < 28; t2 += 2) {
    RNN_STEP(0, 1, t2)
    RNN_STEP(1, 0, t2 + 1)
  }
#undef RNN_STEP

  // ---- epilogue: 2-way K-reduce + bias + store ----
  if (wn < 2) {
    #pragma unroll
    for (int r = 0; r < 4; ++r)
      red[wn][g * 4 + r][li] = fca[r];
  }
  __syncthreads();
  if (tid < 160) {
    const int b = tid / 10, c = tid - b * 10;
    out[(size_t)(blk * 16 + b) * 10 + c] = red[0][b][c] + red[1][b][c] + b_fc[c];
  }
}

extern "C" void kernel_launch(void* const* d_in, const int* in_sizes, int n_in,
                              void* d_out, int out_size, void* d_ws, size_t ws_size,
                              hipStream_t stream) {
  const float* x     = (const float*)d_in[0];
  const float* W_ih1 = (const float*)d_in[1];
  const float* W_hh1 = (const float*)d_in[2];
  const float* b_ih1 = (const float*)d_in[3];
  const float* b_hh1 = (const float*)d_in[4];
  const float* W_ih2 = (const float*)d_in[5];
  const float* W_hh2 = (const float*)d_in[6];
  const float* b_ih2 = (const float*)d_in[7];
  const float* b_hh2 = (const float*)d_in[8];
  const float* W_fc  = (const float*)d_in[9];
  const float* b_fc  = (const float*)d_in[10];
  unsigned short* ws = (unsigned short*)d_ws;

  cvt_weights<<<(WS_U16 + 255) / 256, 256, 0, stream>>>(W_ih1, W_hh1, W_ih2, W_hh2, W_fc, ws);
  rnn_mfma17<<<NBLK, NTHR, 0, stream>>>(x, ws, b_ih1, b_hh1, b_ih2, b_hh2, b_fc,
                                        (float*)d_out);
}